// Round 4
// baseline (529.367 us; speedup 1.0000x reference)
//
#include <hip/hip_runtime.h>

// n_class=32, n_support=16, D=1024; Q=512 query rows. Output (512,32,1024) fp32.
// Trans/VALU-bound: 268M tanh = mul + exp2 + add + rcp + add each.
// R1: fp32 LDS (64KB) -> 2 blocks/CU, Occ=20%, VALUBusy=66%, conflicts 1.7e7 -> 93.6us.
// R3: no-LDS + partial unroll -> sc[] in scratch + nt-store amplification -> 124us. NEVER partial-unroll an indexed array.
// R4: fp16 support in LDS (32KB), full unrolls, normal stores.
constexpr int NC = 32, NS = 16, NQ = 512, D = 1024;
constexpr int QPW = 2;           // queries per wave
constexpr int QPB = 8;           // 4 waves x 2 queries

typedef float    vfloat4 __attribute__((ext_vector_type(4)));
typedef _Float16 vhalf4  __attribute__((ext_vector_type(4)));
typedef _Float16 vhalf8  __attribute__((ext_vector_type(8)));

__global__ __launch_bounds__(256, 4)
void proto_attn_kernel(const float* __restrict__ data, float* __restrict__ out) {
    const int c    = blockIdx.x;
    const int qt   = blockIdx.y;
    const int tid  = threadIdx.x;
    const int wave = tid >> 6;
    const int lane = tid & 63;

    // tanh(x) = 1 - 2/(exp2(K*x)+1),  K = 2*log2(e)
    const float Kc  = 2.88539008177792681472f;
    const float L2E = 1.44269504088896340736f;

    // ---- stage support[c] into LDS as fp16: 16x1024x2B = 32 KB ----
    __shared__ vhalf4 suph[NS * D / 4];
    {
        const vfloat4* sg = reinterpret_cast<const vfloat4*>(data + (size_t)c * NS * D);
        #pragma unroll
        for (int i = 0; i < 16; ++i) {
            vfloat4 v = sg[tid + 256 * i];
            vhalf4 h = { (_Float16)v.x, (_Float16)v.y, (_Float16)v.z, (_Float16)v.w };
            suph[tid + 256 * i] = h;   // ds_write_b64, lane-contiguous
        }
    }
    __syncthreads();

    const int q0 = qt * QPB + wave * QPW;

    // ---- load 2 query rows, pre-scaled by K; layout matches half8 LDS reads ----
    // element d = (lane + 64*j)*8 + k
    float q[QPW][2][8];
    #pragma unroll
    for (int qi = 0; qi < QPW; ++qi) {
        const vfloat4* qg = reinterpret_cast<const vfloat4*>(
            data + (size_t)(NC * NS + q0 + qi) * D);
        #pragma unroll
        for (int j = 0; j < 2; ++j) {
            vfloat4 a = qg[2 * (lane + 64 * j)];
            vfloat4 b = qg[2 * (lane + 64 * j) + 1];
            q[qi][j][0] = a.x * Kc; q[qi][j][1] = a.y * Kc;
            q[qi][j][2] = a.z * Kc; q[qi][j][3] = a.w * Kc;
            q[qi][j][4] = b.x * Kc; q[qi][j][5] = b.y * Kc;
            q[qi][j][6] = b.z * Kc; q[qi][j][7] = b.w * Kc;
        }
    }

    const vhalf8* sh8 = reinterpret_cast<const vhalf8*>(suph);

    // ---- scores: sc[qi][s] = D - 2 * sum_d 1/(exp2(sup*qK)+1) ----
    float sc[QPW][NS];
    #pragma unroll
    for (int s = 0; s < NS; ++s) {
        float r0 = 0.f, r1 = 0.f;
        #pragma unroll
        for (int j = 0; j < 2; ++j) {
            const vhalf8 h = sh8[s * (D / 8) + lane + 64 * j];  // ds_read_b128
            #pragma unroll
            for (int k = 0; k < 8; ++k) {
                const float sv = (float)h[k];
                r0 += __builtin_amdgcn_rcpf(__builtin_amdgcn_exp2f(sv * q[0][j][k]) + 1.f);
                r1 += __builtin_amdgcn_rcpf(__builtin_amdgcn_exp2f(sv * q[1][j][k]) + 1.f);
            }
        }
        #pragma unroll
        for (int m = 32; m >= 1; m >>= 1) {
            r0 += __shfl_xor(r0, m, 64);
            r1 += __shfl_xor(r1, m, 64);
        }
        sc[0][s] = (float)D - 2.f * r0;
        sc[1][s] = (float)D - 2.f * r1;
    }

    // ---- softmax over s (replicated per lane), fold normalization into sc ----
    #pragma unroll
    for (int qi = 0; qi < QPW; ++qi) {
        float m = sc[qi][0];
        #pragma unroll
        for (int s = 1; s < NS; ++s) m = fmaxf(m, sc[qi][s]);
        float sum = 0.f;
        #pragma unroll
        for (int s = 0; s < NS; ++s) {
            sc[qi][s] = __builtin_amdgcn_exp2f((sc[qi][s] - m) * L2E);
            sum += sc[qi][s];
        }
        const float inv = __builtin_amdgcn_rcpf(sum);
        #pragma unroll
        for (int s = 0; s < NS; ++s) sc[qi][s] *= inv;
    }

    // ---- proto: out[q,c,:] = sum_s att[s] * support[c,s,:] ----
    float acc[QPW][2][8];
    #pragma unroll
    for (int qi = 0; qi < QPW; ++qi)
        #pragma unroll
        for (int j = 0; j < 2; ++j)
            #pragma unroll
            for (int k = 0; k < 8; ++k)
                acc[qi][j][k] = 0.f;

    #pragma unroll
    for (int s = 0; s < NS; ++s) {
        const float a0 = sc[0][s];
        const float a1 = sc[1][s];
        #pragma unroll
        for (int j = 0; j < 2; ++j) {
            const vhalf8 h = sh8[s * (D / 8) + lane + 64 * j];
            #pragma unroll
            for (int k = 0; k < 8; ++k) {
                const float sv = (float)h[k];
                acc[0][j][k] = fmaf(a0, sv, acc[0][j][k]);
                acc[1][j][k] = fmaf(a1, sv, acc[1][j][k]);
            }
        }
    }

    #pragma unroll
    for (int qi = 0; qi < QPW; ++qi) {
        vfloat4* og = reinterpret_cast<vfloat4*>(out + ((size_t)(q0 + qi) * NC + c) * D);
        #pragma unroll
        for (int j = 0; j < 2; ++j) {
            vfloat4 lo = { acc[qi][j][0], acc[qi][j][1], acc[qi][j][2], acc[qi][j][3] };
            vfloat4 hi = { acc[qi][j][4], acc[qi][j][5], acc[qi][j][6], acc[qi][j][7] };
            og[2 * (lane + 64 * j)]     = lo;
            og[2 * (lane + 64 * j) + 1] = hi;
        }
    }
}

extern "C" void kernel_launch(void* const* d_in, const int* in_sizes, int n_in,
                              void* d_out, int out_size, void* d_ws, size_t ws_size,
                              hipStream_t stream) {
    (void)in_sizes; (void)n_in; (void)out_size; (void)d_ws; (void)ws_size;
    const float* data = (const float*)d_in[0];
    float* out = (float*)d_out;
    dim3 grid(NC, NQ / QPB);   // 32 x 64 = 2048 blocks
    proto_attn_kernel<<<grid, dim3(256), 0, stream>>>(data, out);
}

// Round 5
// 244.736 us; speedup vs baseline: 2.1630x; 2.1630x over previous
//
#include <hip/hip_runtime.h>

// n_class=32, n_support=16, D=1024; Q=512 query rows. Output (512,32,1024) fp32.
// Trans/VALU-bound: 268M tanh = mul + exp2 + add + rcp + add each.
// R1: fp32 LDS 64KB, (256,2): 92 VGPR, Occ 20%, VALU 66%, 93.6us.
// R3: no-LDS + partial unroll -> scratch -> 124us.
// R4: fp16 LDS + __launch_bounds__(256,4) -> VGPR capped at 64 -> total spill,
//     622MB writes, 494us. LESSON: min-waves arg below register need = scratch death.
// R5: R4 structure, bound relaxed to (256,2). Expect ~110-130 VGPR, no spill.
constexpr int NC = 32, NS = 16, NQ = 512, D = 1024;
constexpr int QPW = 2;           // queries per wave
constexpr int QPB = 8;           // 4 waves x 2 queries

typedef float    vfloat4 __attribute__((ext_vector_type(4)));
typedef _Float16 vhalf4  __attribute__((ext_vector_type(4)));
typedef _Float16 vhalf8  __attribute__((ext_vector_type(8)));

__global__ __launch_bounds__(256, 2)
void proto_attn_kernel(const float* __restrict__ data, float* __restrict__ out) {
    const int c    = blockIdx.x;
    const int qt   = blockIdx.y;
    const int tid  = threadIdx.x;
    const int wave = tid >> 6;
    const int lane = tid & 63;

    // tanh(x) = 1 - 2/(exp2(K*x)+1),  K = 2*log2(e)
    const float Kc  = 2.88539008177792681472f;
    const float L2E = 1.44269504088896340736f;

    // ---- stage support[c] into LDS as fp16: 16x1024x2B = 32 KB ----
    __shared__ vhalf4 suph[NS * D / 4];
    {
        const vfloat4* sg = reinterpret_cast<const vfloat4*>(data + (size_t)c * NS * D);
        #pragma unroll
        for (int i = 0; i < 16; ++i) {
            vfloat4 v = sg[tid + 256 * i];
            vhalf4 h = { (_Float16)v.x, (_Float16)v.y, (_Float16)v.z, (_Float16)v.w };
            suph[tid + 256 * i] = h;   // ds_write_b64, lane-contiguous
        }
    }
    __syncthreads();

    const int q0 = qt * QPB + wave * QPW;

    // ---- load 2 query rows, pre-scaled by K; layout matches half8 LDS reads ----
    // element d = (lane + 64*j)*8 + k
    float q[QPW][2][8];
    #pragma unroll
    for (int qi = 0; qi < QPW; ++qi) {
        const vfloat4* qg = reinterpret_cast<const vfloat4*>(
            data + (size_t)(NC * NS + q0 + qi) * D);
        #pragma unroll
        for (int j = 0; j < 2; ++j) {
            vfloat4 a = qg[2 * (lane + 64 * j)];
            vfloat4 b = qg[2 * (lane + 64 * j) + 1];
            q[qi][j][0] = a.x * Kc; q[qi][j][1] = a.y * Kc;
            q[qi][j][2] = a.z * Kc; q[qi][j][3] = a.w * Kc;
            q[qi][j][4] = b.x * Kc; q[qi][j][5] = b.y * Kc;
            q[qi][j][6] = b.z * Kc; q[qi][j][7] = b.w * Kc;
        }
    }

    const vhalf8* sh8 = reinterpret_cast<const vhalf8*>(suph);

    // ---- scores: sc[qi][s] = D - 2 * sum_d 1/(exp2(sup*qK)+1) ----
    float sc[QPW][NS];
    #pragma unroll
    for (int s = 0; s < NS; ++s) {
        float r0 = 0.f, r1 = 0.f;
        #pragma unroll
        for (int j = 0; j < 2; ++j) {
            const vhalf8 h = sh8[s * (D / 8) + lane + 64 * j];  // ds_read_b128
            #pragma unroll
            for (int k = 0; k < 8; ++k) {
                const float sv = (float)h[k];
                r0 += __builtin_amdgcn_rcpf(__builtin_amdgcn_exp2f(sv * q[0][j][k]) + 1.f);
                r1 += __builtin_amdgcn_rcpf(__builtin_amdgcn_exp2f(sv * q[1][j][k]) + 1.f);
            }
        }
        #pragma unroll
        for (int m = 32; m >= 1; m >>= 1) {
            r0 += __shfl_xor(r0, m, 64);
            r1 += __shfl_xor(r1, m, 64);
        }
        sc[0][s] = (float)D - 2.f * r0;
        sc[1][s] = (float)D - 2.f * r1;
    }

    // ---- softmax over s (replicated per lane), fold normalization into sc ----
    #pragma unroll
    for (int qi = 0; qi < QPW; ++qi) {
        float m = sc[qi][0];
        #pragma unroll
        for (int s = 1; s < NS; ++s) m = fmaxf(m, sc[qi][s]);
        float sum = 0.f;
        #pragma unroll
        for (int s = 0; s < NS; ++s) {
            sc[qi][s] = __builtin_amdgcn_exp2f((sc[qi][s] - m) * L2E);
            sum += sc[qi][s];
        }
        const float inv = __builtin_amdgcn_rcpf(sum);
        #pragma unroll
        for (int s = 0; s < NS; ++s) sc[qi][s] *= inv;
    }

    // ---- proto: out[q,c,:] = sum_s att[s] * support[c,s,:] ----
    float acc[QPW][2][8];
    #pragma unroll
    for (int qi = 0; qi < QPW; ++qi)
        #pragma unroll
        for (int j = 0; j < 2; ++j)
            #pragma unroll
            for (int k = 0; k < 8; ++k)
                acc[qi][j][k] = 0.f;

    #pragma unroll
    for (int s = 0; s < NS; ++s) {
        const float a0 = sc[0][s];
        const float a1 = sc[1][s];
        #pragma unroll
        for (int j = 0; j < 2; ++j) {
            const vhalf8 h = sh8[s * (D / 8) + lane + 64 * j];
            #pragma unroll
            for (int k = 0; k < 8; ++k) {
                const float sv = (float)h[k];
                acc[0][j][k] = fmaf(a0, sv, acc[0][j][k]);
                acc[1][j][k] = fmaf(a1, sv, acc[1][j][k]);
            }
        }
    }

    #pragma unroll
    for (int qi = 0; qi < QPW; ++qi) {
        vfloat4* og = reinterpret_cast<vfloat4*>(out + ((size_t)(q0 + qi) * NC + c) * D);
        #pragma unroll
        for (int j = 0; j < 2; ++j) {
            vfloat4 lo = { acc[qi][j][0], acc[qi][j][1], acc[qi][j][2], acc[qi][j][3] };
            vfloat4 hi = { acc[qi][j][4], acc[qi][j][5], acc[qi][j][6], acc[qi][j][7] };
            og[2 * (lane + 64 * j)]     = lo;
            og[2 * (lane + 64 * j) + 1] = hi;
        }
    }
}

extern "C" void kernel_launch(void* const* d_in, const int* in_sizes, int n_in,
                              void* d_out, int out_size, void* d_ws, size_t ws_size,
                              hipStream_t stream) {
    (void)in_sizes; (void)n_in; (void)out_size; (void)d_ws; (void)ws_size;
    const float* data = (const float*)d_in[0];
    float* out = (float*)d_out;
    dim3 grid(NC, NQ / QPB);   // 32 x 64 = 2048 blocks
    proto_attn_kernel<<<grid, dim3(256), 0, stream>>>(data, out);
}